// Round 6
// baseline (319.519 us; speedup 1.0000x reference)
//
#include <hip/hip_runtime.h>

#define DIN 128
#define DOUT 64
#define SH 8            // nodes per bucket = 256
#define CAP 8192        // slots per bucket (avg ~4096, +64 sigma headroom)
#define BMAX 512
#define XS_STRIDE (DIN + 4)

typedef unsigned short ushort_t;

__device__ __forceinline__ ushort_t f2bf(float f) {
    union { float f; unsigned u; } v; v.f = f;
    unsigned r = v.u + 0x7FFF + ((v.u >> 16) & 1);   // round-nearest-even
    return (ushort_t)(r >> 16);
}
__device__ __forceinline__ float bf2f(ushort_t h) {
    union { unsigned u; float f; } v; v.u = ((unsigned)h) << 16;
    return v.f;
}

// ---------- pass A: bin edges by dst>>SH, packed (ldst<<17)|src ----------
__global__ __launch_bounds__(256) void bin_kernel(const int* __restrict__ src,
                                                  const int* __restrict__ dst,
                                                  int* __restrict__ cursor,
                                                  int* __restrict__ binned, int E, int B) {
    __shared__ int hist_s[BMAX], gbase_s[BMAX], cur_s[BMAX];
    for (int i = threadIdx.x; i < B; i += 256) { hist_s[i] = 0; cur_s[i] = 0; }
    __syncthreads();
    int e0 = blockIdx.x * 4096;
    int e1 = min(e0 + 4096, E);
    for (int e = e0 + threadIdx.x; e < e1; e += 256)
        atomicAdd(&hist_s[dst[e] >> SH], 1);
    __syncthreads();
    for (int b = threadIdx.x; b < B; b += 256) {
        int h = hist_s[b];
        gbase_s[b] = h ? atomicAdd(&cursor[b], h) : 0;
    }
    __syncthreads();
    for (int e = e0 + threadIdx.x; e < e1; e += 256) {
        int d = dst[e], s = src[e];
        int b = d >> SH;
        int off  = atomicAdd(&cur_s[b], 1);
        int slot = gbase_s[b] + off;
        if (slot < (b + 1) * CAP)
            binned[slot] = ((d & ((1 << SH) - 1)) << 17) | s;
    }
}

// also zeroes the 16-int csr_src pad (read speculatively by gather tail batches)
__global__ void init_cursor_kernel(int* cursor, int B, int* csr_pad) {
    int b = blockIdx.x * 256 + threadIdx.x;
    if (b < B) cursor[b] = b * CAP;
    if (b < 16) csr_pad[b] = 0;
}

// exclusive scan of bucket counts -> bucket_base; row_ptr[N] = total
__global__ __launch_bounds__(BMAX) void bucket_scan_kernel(const int* __restrict__ cursor,
                                                           int* __restrict__ bucket_base,
                                                           int* __restrict__ row_ptr,
                                                           int B, int N) {
    __shared__ int sh[BMAX];
    int t = threadIdx.x;
    int c = 0;
    if (t < B) { c = cursor[t] - t * CAP; if (c > CAP) c = CAP; }
    sh[t] = c;
    __syncthreads();
    for (int off = 1; off < BMAX; off <<= 1) {
        int v = (t >= off) ? sh[t - off] : 0;
        __syncthreads();
        sh[t] += v;
        __syncthreads();
    }
    if (t < B) bucket_base[t] = sh[t] - c;  // exclusive
    if (t == 0) row_ptr[N] = sh[B - 1];     // total (== E)
}

// ---------- pass B: per-bucket CSR build + row_ptr + dinv ----------
__global__ __launch_bounds__(256) void csr_kernel(const int* __restrict__ binned,
                                                  const int* __restrict__ cursor,
                                                  const int* __restrict__ bucket_base,
                                                  int* __restrict__ row_ptr,
                                                  float* __restrict__ dinv,
                                                  int* __restrict__ csr_src, int N) {
    __shared__ int cnt_s[256], off_s[256];
    int b = blockIdx.x;
    int t = threadIdx.x;
    int ecnt = cursor[b] - b * CAP; if (ecnt > CAP) ecnt = CAP;
    int base = bucket_base[b];
    const int* eb = binned + (size_t)b * CAP;
    cnt_s[t] = 0;
    __syncthreads();
    for (int i = t; i < ecnt; i += 256)
        atomicAdd(&cnt_s[eb[i] >> 17], 1);
    __syncthreads();
    int myc = cnt_s[t];
    off_s[t] = myc;
    __syncthreads();
    for (int off = 1; off < 256; off <<= 1) {
        int v = (t >= off) ? off_s[t - off] : 0;
        __syncthreads();
        off_s[t] += v;
        __syncthreads();
    }
    int excl = off_s[t] - myc;
    int node = (b << SH) + t;
    if (node < N) {
        row_ptr[node] = base + excl;
        dinv[node] = rsqrtf((float)myc + 1.0f);  // +1 = self loop
    }
    __syncthreads();
    off_s[t] = base + excl;   // global write cursor for this node
    __syncthreads();
    for (int i = t; i < ecnt; i += 256) {
        int p = eb[i];
        int slot = atomicAdd(&off_s[p >> 17], 1);
        csr_src[slot] = p & 0x1FFFF;
    }
}

// ---------- projection: y0' = dinv * (x @ W^T), stored bf16 ----------
__global__ __launch_bounds__(256) void gemm_kernel(const float* __restrict__ x,
                                                   const float* __restrict__ W,
                                                   const float* __restrict__ dinv,
                                                   ushort_t* __restrict__ yb, int N) {
    __shared__ float Ws[DIN * DOUT];          // [k][o], 32 KB
    __shared__ float xs[64 * XS_STRIDE];      // 64 rows, padded
    int tid  = threadIdx.x;
    int row0 = blockIdx.x * 64;

    // stage W transposed with LINEAR LDS writes (conflict-free)
    for (int j = tid; j < DIN * DOUT; j += 256)
        Ws[j] = W[(j & 63) * DIN + (j >> 6)];

    // stage x tile: coalesced float4 global reads
    for (int j = tid; j < 64 * DIN / 4; j += 256) {
        int r  = j >> 5;
        int c4 = (j & 31) * 4;
        int grow = row0 + r;
        float4 v = {0.f, 0.f, 0.f, 0.f};
        if (grow < N) v = *(const float4*)&x[(size_t)grow * DIN + c4];
        *(float4*)&xs[r * XS_STRIDE + c4] = v;
    }
    __syncthreads();

    int g    = tid & 15;
    int rgl  = (tid >> 4) & 3;
    int wave = tid >> 6;
    int rloc = wave * 16 + rgl * 4;

    float4 acc[4] = {};
    for (int kk = 0; kk < DIN; kk += 4) {
        float4 wv0 = *(const float4*)&Ws[(kk + 0) * DOUT + g * 4];
        float4 wv1 = *(const float4*)&Ws[(kk + 1) * DOUT + g * 4];
        float4 wv2 = *(const float4*)&Ws[(kk + 2) * DOUT + g * 4];
        float4 wv3 = *(const float4*)&Ws[(kk + 3) * DOUT + g * 4];
        #pragma unroll
        for (int r = 0; r < 4; ++r) {
            float4 xv = *(const float4*)&xs[(rloc + r) * XS_STRIDE + kk];
            acc[r].x += xv.x * wv0.x + xv.y * wv1.x + xv.z * wv2.x + xv.w * wv3.x;
            acc[r].y += xv.x * wv0.y + xv.y * wv1.y + xv.z * wv2.y + xv.w * wv3.y;
            acc[r].z += xv.x * wv0.z + xv.y * wv1.z + xv.z * wv2.z + xv.w * wv3.z;
            acc[r].w += xv.x * wv0.w + xv.y * wv1.w + xv.z * wv2.w + xv.w * wv3.w;
        }
    }
    #pragma unroll
    for (int r = 0; r < 4; ++r) {
        int grow = row0 + rloc + r;
        if (grow < N) {
            float dv = dinv[grow];
            ushort4 o;
            o.x = f2bf(acc[r].x * dv); o.y = f2bf(acc[r].y * dv);
            o.z = f2bf(acc[r].z * dv); o.w = f2bf(acc[r].w * dv);
            *(ushort4*)&yb[(size_t)grow * DOUT + g * 4] = o;
        }
    }
}

// ---------- pull-gather hop (pre-scaled state): one wave per dst row ----------
// Batched-16 speculative loads (MLP) + scalar (SGPR) index path.
// in: y'[s] (bf16). z = y'[row] + sum_{s in N(row)} y'[s]
// FINAL=0: write y1'[row] = dinv^2 * z (bf16)
// FINAL=1: y2 = dinv * z; emb = y2 + bias; out = log_softmax(emb)
template <int FINAL>
__global__ __launch_bounds__(256) void gather_kernel(const int* __restrict__ row_ptr,
                                                     const int* __restrict__ csr_src,
                                                     const float* __restrict__ dinv,
                                                     const ushort_t* __restrict__ yin,
                                                     const float* __restrict__ bias,
                                                     ushort_t* __restrict__ yout,
                                                     float* __restrict__ out,
                                                     float* __restrict__ emb, int N) {
    int row = blockIdx.x * 4 + (threadIdx.x >> 6);   // wave-uniform
    if (row >= N) return;
    int lane = threadIdx.x & 63;
    int end_v   = row_ptr[row + 1];                  // VGPR copy (per-lane mask compare)
    int start_s = __builtin_amdgcn_readfirstlane(row_ptr[row]);
    int end_s   = __builtin_amdgcn_readfirstlane(end_v);

    float acc = bf2f(yin[(size_t)row * DOUT + lane]);  // self loop (pre-scaled)
    const ushort_t* ylane = yin + lane;

    for (int b = start_s; b < end_s; b += 16) {
        float v[16];
        // 16 speculative loads, all in flight before any mask/add (MLP).
        // csr_src[b+j] is s_load (wave-uniform addr); pad [E,E+16) = 0 -> safe.
        #pragma unroll
        for (int j = 0; j < 16; ++j) {
            int s = __builtin_amdgcn_readfirstlane(csr_src[b + j]);
            ushort_t h = ylane[(size_t)s * DOUT];
            v[j] = (b + j < end_v) ? bf2f(h) : 0.f;   // VGPR compare -> cndmask
        }
        float t0 = (v[0] + v[1]) + (v[2] + v[3]);
        float t1 = (v[4] + v[5]) + (v[6] + v[7]);
        float t2 = (v[8] + v[9]) + (v[10] + v[11]);
        float t3 = (v[12] + v[13]) + (v[14] + v[15]);
        acc += (t0 + t1) + (t2 + t3);
    }

    float dv = dinv[row];
    if (!FINAL) {
        yout[(size_t)row * DOUT + lane] = f2bf(dv * dv * acc);
    } else {
        float e = dv * acc + bias[lane];
        emb[(size_t)row * DOUT + lane] = e;
        float m = e;
        for (int o = 32; o; o >>= 1) m = fmaxf(m, __shfl_xor(m, o, 64));
        float ex = expf(e - m);
        float ss = ex;
        for (int o = 32; o; o >>= 1) ss += __shfl_xor(ss, o, 64);
        out[(size_t)row * DOUT + lane] = e - m - logf(ss);
    }
}

extern "C" void kernel_launch(void* const* d_in, const int* in_sizes, int n_in,
                              void* d_out, int out_size, void* d_ws, size_t ws_size,
                              hipStream_t stream) {
    const float* x    = (const float*)d_in[0];
    const int*   edge = (const int*)d_in[1];
    const float* W    = (const float*)d_in[2];
    const float* b    = (const float*)d_in[3];

    const int N = in_sizes[0] / DIN;   // 100000
    const int E = in_sizes[1] / 2;     // 1600000
    const int* src = edge;
    const int* dst = edge + E;

    float* out_ptr = (float*)d_out;                // [N,64] log_softmax
    float* emb_ptr = out_ptr + (size_t)N * DOUT;   // [N,64] emb

    const int B = (N + (1 << SH) - 1) >> SH;       // 391 buckets

    // workspace layout (~33 MB):
    //   cursor[512] | bucket_base[512] | row_ptr[N+1] | dinv[N] | csr_src[E+16 pad] |
    //   arena: binned[B*CAP] ints (CSR build), then y0b,y1b bf16 (gathers)
    int*     cursor      = (int*)d_ws;
    int*     bucket_base = cursor + BMAX;
    int*     row_ptr     = bucket_base + BMAX;
    float*   dinv        = (float*)(row_ptr + N + 1);
    int*     csr_src     = (int*)(dinv + N);
    int*     arena       = csr_src + E + 16;        // +16: csr pad
    int*     binned      = arena;
    ushort_t* y0b        = (ushort_t*)arena;        // aliases binned (dead after csr_kernel)
    ushort_t* y1b        = y0b + (size_t)N * DOUT;

    // 1. CSR by dst (binned, no write amplification) + dinv
    init_cursor_kernel<<<(B + 255) / 256, 256, 0, stream>>>(cursor, B, csr_src + E);
    bin_kernel<<<(E + 4095) / 4096, 256, 0, stream>>>(src, dst, cursor, binned, E, B);
    bucket_scan_kernel<<<1, BMAX, 0, stream>>>(cursor, bucket_base, row_ptr, B, N);
    csr_kernel<<<B, 256, 0, stream>>>(binned, cursor, bucket_base, row_ptr, dinv, csr_src, N);

    // 2. project + pre-scale: y0' = dinv * (x @ W^T)   (bf16)
    gemm_kernel<<<(N + 63) / 64, 256, 0, stream>>>(x, W, dinv, y0b, N);

    // 3. hop 1: y1' = dinv^2 * (y0'[row] + sum y0'[src])   (bf16)
    gather_kernel<0><<<(N + 3) / 4, 256, 0, stream>>>(row_ptr, csr_src, dinv, y0b, b,
                                                      y1b, nullptr, nullptr, N);

    // 4. hop 2 + bias + log_softmax, fused
    gather_kernel<1><<<(N + 3) / 4, 256, 0, stream>>>(row_ptr, csr_src, dinv, y1b, b,
                                                      nullptr, out_ptr, emb_ptr, N);
}